// Round 15
// baseline (82.709 us; speedup 1.0000x reference)
//
#include <hip/hip_runtime.h>
#include <hip/hip_bf16.h>
#include <cstdint>

// Problem constants
#define BROWS 8192
#define DIN   512
#define DH    1024
#define KTOT  1536          // DIN + DH
#define NT    (KTOT / 64)   // 24 K-tiles of 64
// Only gate columns [0,2048) are live: g block [0,1024), i block [1024,2048).
// (reference bug: f_out and o_out both use i_in -> f_in/o_in are dead)

typedef __bf16 bf16x8 __attribute__((ext_vector_type(8)));
typedef __bf16 bf16x4 __attribute__((ext_vector_type(4)));
typedef float  f32x16 __attribute__((ext_vector_type(16)));

__device__ __forceinline__ void load16_to_lds(const void* gptr, void* lptr) {
    __builtin_amdgcn_global_load_lds(
        (const __attribute__((address_space(1))) uint32_t*)gptr,
        (__attribute__((address_space(3))) uint32_t*)lptr,
        16, 0, 0);
}

// ---------- Kernel 1: convert x|h -> bf16 A[8192][1536], PRE-SWIZZLED ----------
__global__ __launch_bounds__(256) void cvtA_kernel(
    const float* __restrict__ x, const float* __restrict__ h,
    __bf16* __restrict__ A) {
    int t = blockIdx.x * 256 + threadIdx.x;   // 8192*192 units of 16B
    int row = t / 192;
    int j = t - row * 192;
    int kg = j * 8;
    const float* src = (kg < DIN) ? (x + (size_t)row * DIN + kg)
                                  : (h + (size_t)row * DH + (kg - DIN));
    float4 u = *(const float4*)src;
    float4 v = *(const float4*)(src + 4);
    bf16x8 o = { (__bf16)u.x, (__bf16)u.y, (__bf16)u.z, (__bf16)u.w,
                 (__bf16)v.x, (__bf16)v.y, (__bf16)v.z, (__bf16)v.w };
    int swz = (j * 16) ^ ((row & 7) << 4);
    *(bf16x8*)((char*)A + (size_t)row * 3072 + swz) = o;
}

// ---------- Kernel 2: transpose+convert W cols [0,2048) -> bf16 Bt[2048][1536], PRE-SWIZZLED ----------
__global__ __launch_bounds__(256) void cvtB_kernel(
    const float* __restrict__ Wx, const float* __restrict__ Wh,
    __bf16* __restrict__ Bt) {
    __shared__ float tile[32][33];
    int k0 = blockIdx.x * 32;
    int n0 = blockIdx.y * 32;
    int tx = threadIdx.x;   // 0..31
    int ty = threadIdx.y;   // 0..7
#pragma unroll
    for (int i = 0; i < 4; ++i) {
        int k = k0 + ty + 8 * i;
        float v = (k < DIN) ? Wx[(size_t)k * 4096 + n0 + tx]
                            : Wh[(size_t)(k - DIN) * 4096 + n0 + tx];
        tile[ty + 8 * i][tx] = v;
    }
    __syncthreads();
    int n = n0 + tx;
    int kk = ty * 4;
    bf16x4 o = { (__bf16)tile[kk][tx], (__bf16)tile[kk + 1][tx],
                 (__bf16)tile[kk + 2][tx], (__bf16)tile[kk + 3][tx] };
    int swz = ((k0 + kk) * 2) ^ ((n & 7) << 4);
    *(bf16x4*)((char*)Bt + (size_t)n * 3072 + swz) = o;
}

// ---------- Kernel 3: R9 chassis + 32x32x16 MFMA + fused LSTM epilogue ----------
// Tile 256(M) x 128(n') x {g,i}; 8 waves = 4M x 2N; wave = 64M x 64n' x {g,i}.
// MFMA shape 32x32x16 (2495 TF ceiling, half the instrs of 16x16x32).
// Schedule/staging/vmcnt identical to R9 (proven): stage A0,A1,Bg,Bi;
// P1 vmcnt(2), P3 vmcnt(4); tail 2 -> 0.

#define BARRIER  do { __builtin_amdgcn_sched_barrier(0); __builtin_amdgcn_s_barrier(); __builtin_amdgcn_sched_barrier(0); } while (0)
#define VMW(n)   do { asm volatile("s_waitcnt vmcnt(" #n ")" ::: "memory"); __builtin_amdgcn_sched_barrier(0); } while (0)
#define LGKM0    do { asm volatile("s_waitcnt lgkmcnt(0)" ::: "memory"); __builtin_amdgcn_sched_barrier(0); } while (0)

#define STAGE_A(buf, mh, kt) do {                                              \
    const char* g0_ = Ab + (size_t)(brow + (mh) * 128 + r0) * 3072             \
                         + (size_t)(kt) * 128 + cb;                            \
    char* l0_ = sAb + (buf) * 32768 + ((mh) * 128 + r0) * 128 + cb;            \
    load16_to_lds(g0_, l0_);                                                   \
    load16_to_lds(g0_ + 64 * 3072, l0_ + 64 * 128);                            \
} while (0)

#define STAGE_B(buf, half, kt) do {                                            \
    const char* g0_ = Bb + (size_t)((half) * 1024 + bnp + r0) * 3072           \
                         + (size_t)(kt) * 128 + cb;                            \
    char* l0_ = sBb + (buf) * 32768 + ((half) * 128 + r0) * 128 + cb;          \
    load16_to_lds(g0_, l0_);                                                   \
    load16_to_lds(g0_ + 64 * 3072, l0_ + 64 * 128);                            \
} while (0)

// 32x32x16 A-frag: lane l -> row l&31, k-elems (l>>5)*8..+8 of k-frag kf.
// LDS byte = row*128 + ((kf*32 + (l>>5)*16) ^ ((row&7)<<4)).
#define READ_A32(dst, c, mh)                                                   \
    _Pragma("unroll")                                                          \
    for (int kf_ = 0; kf_ < 4; ++kf_) {                                        \
        int row_ = wrow + (mh) * 32 + l31;                                     \
        int kb_ = (kf_ * 32 + hi16) ^ ((l31 & 7) << 4);                        \
        dst[kf_] = *(const bf16x8*)(sAb + (c) * 32768 + row_ * 128 + kb_);     \
    }

#define READ_B32(dst, c, half)                                                 \
    _Pragma("unroll")                                                          \
    for (int nq_ = 0; nq_ < 2; ++nq_) {                                        \
        _Pragma("unroll")                                                      \
        for (int kf_ = 0; kf_ < 4; ++kf_) {                                    \
            int row_ = (half) * 128 + wcol + nq_ * 32 + l31;                   \
            int kb_ = (kf_ * 32 + hi16) ^ ((l31 & 7) << 4);                    \
            dst[nq_][kf_] = *(const bf16x8*)(sBb + (c) * 32768 + row_ * 128    \
                                             + kb_);                           \
        }                                                                      \
    }

// 8 MFMA (kf outer, nq inner: dependent-chain distance 2)
#define MMA32(ACC, MH, AF, BF) do {                                            \
    __builtin_amdgcn_s_setprio(1);                                             \
    _Pragma("unroll")                                                          \
    for (int kf_ = 0; kf_ < 4; ++kf_) {                                        \
        _Pragma("unroll")                                                      \
        for (int nq_ = 0; nq_ < 2; ++nq_) {                                    \
            ACC[MH][nq_] = __builtin_amdgcn_mfma_f32_32x32x16_bf16(            \
                AF[kf_], BF[nq_][kf_], ACC[MH][nq_], 0, 0, 0);                 \
        }                                                                      \
    }                                                                          \
    __builtin_amdgcn_s_setprio(0);                                             \
    __builtin_amdgcn_sched_barrier(0);                                         \
} while (0)

__global__ __launch_bounds__(512, 2) void lstm_gemm_kernel(
    const __bf16* __restrict__ A,    // [8192][1536] pre-swizzled
    const __bf16* __restrict__ Bt,   // [2048][1536] pre-swizzled
    const float* __restrict__ bias,  // [4096]
    const float* __restrict__ c_in,  // [8192][1024]
    float* __restrict__ out_h,       // [8192][1024]
    float* __restrict__ out_c) {     // [8192][1024]
    __shared__ __bf16 sA[2][256][64];   // 64 KiB
    __shared__ __bf16 sB[2][256][64];   // 64 KiB (g rows 0-127, i rows 128-255)

    const int tid  = threadIdx.x;
    const int lane = tid & 63;
    const int wid  = tid >> 6;
    const int wr   = wid & 3;          // 4 wave-rows
    const int wc   = wid >> 2;         // 2 wave-cols

    // XCD-contiguous band map (R9-proven: FETCH 67 MB)
    const int bid   = blockIdx.x;              // 0..255
    const int band  = (bid & 7) * 4 + ((bid >> 3) & 3);  // 0..31
    const int panel = bid >> 5;                          // 0..7
    const int brow  = band * 256;
    const int bnp   = panel * 128;

    const int l31  = lane & 31;
    const int hi   = lane >> 5;        // 0..1
    const int hi16 = hi * 16;
    const int wrow = wr * 64;
    const int wcol = wc * 64;

    // staging lane mapping: per wave, LDS dst = uniform base + lane*16
    const int r0 = tid >> 3;           // 0..63
    const int cb = (tid & 7) * 16;     // 0..112

    const char* Ab = (const char*)A;
    const char* Bb = (const char*)Bt;
    char* sAb = (char*)&sA[0][0][0];
    char* sBb = (char*)&sB[0][0][0];

    f32x16 accg[2][2], acci[2][2];
#pragma unroll
    for (int mh = 0; mh < 2; ++mh)
#pragma unroll
        for (int nq = 0; nq < 2; ++nq)
#pragma unroll
            for (int j = 0; j < 16; ++j) {
                accg[mh][nq][j] = 0.f;
                acci[mh][nq][j] = 0.f;
            }

    bf16x8 aF0[4], aF1[4], bgF[2][4], biF[2][4];

    // prologue: stage tile 0.  Queue order per tile: A0, A1, Bg, Bi.
    STAGE_A(0, 0, 0);
    STAGE_A(0, 1, 0);
    STAGE_B(0, 0, 0);
    STAGE_B(0, 1, 0);

    for (int t = 0; t < NT - 1; ++t) {
        const int c  = t & 1;
        const int nb = c ^ 1;
        // P1: needs A0, A1, Bg of tile t  (oldest 6 of 8 in flight)
        VMW(2); BARRIER;
        READ_A32(aF0, c, 0);
        READ_B32(bgF, c, 0);
        STAGE_A(nb, 0, t + 1);
        BARRIER; LGKM0;
        MMA32(accg, 0, aF0, bgF);
        // P2: no new LDS data needed
        BARRIER;
        READ_A32(aF1, c, 1);
        STAGE_A(nb, 1, t + 1);
        BARRIER; LGKM0;
        MMA32(accg, 1, aF1, bgF);
        // P3: needs Bi of tile t  (queue: [Bi(t), A0(t+1), A1(t+1)] = 6)
        VMW(4); BARRIER;
        READ_B32(biF, c, 1);
        STAGE_B(nb, 0, t + 1);
        BARRIER; LGKM0;
        MMA32(acci, 0, aF0, biF);
        // P4: nothing new needed
        BARRIER;
        STAGE_B(nb, 1, t + 1);
        BARRIER;
        MMA32(acci, 1, aF1, biF);
    }
    {   // last tile: exact drains 2 -> 0, no prefetch
        const int c = (NT - 1) & 1;
        VMW(2); BARRIER;
        READ_A32(aF0, c, 0);
        READ_B32(bgF, c, 0);
        BARRIER; LGKM0;
        MMA32(accg, 0, aF0, bgF);
        BARRIER;
        READ_A32(aF1, c, 1);
        BARRIER; LGKM0;
        MMA32(accg, 1, aF1, bgF);
        VMW(0); BARRIER;
        READ_B32(biF, c, 1);
        BARRIER; LGKM0;
        MMA32(acci, 0, aF0, biF);
        MMA32(acci, 1, aF1, biF);
    }

    // Epilogue. 32x32 C/D layout (m74/m101): col = lane&31,
    // row = (r&3) + 8*(r>>2) + 4*(lane>>5), r in [0,16).
    const int R0 = brow + wrow;
    const int C0 = bnp + wcol;
#pragma unroll
    for (int nq = 0; nq < 2; ++nq) {
        const int col = C0 + nq * 32 + l31;
        const float bg = bias[col];
        const float bi = bias[1024 + col];
#pragma unroll
        for (int mh = 0; mh < 2; ++mh) {
#pragma unroll
            for (int r = 0; r < 16; ++r) {
                const int row = R0 + mh * 32 + (r & 3) + 8 * (r >> 2) + 4 * hi;
                const float g_in = accg[mh][nq][r] + bg;
                const float i_in = acci[mh][nq][r] + bi;
                const float s  = 1.0f / (1.0f + __expf(-i_in));
                const float tg = 2.0f / (1.0f + __expf(-2.0f * g_in)) - 1.0f;
                const float cv = c_in[(size_t)row * DH + col];
                const float cn = s * (tg + cv);
                const float hn = (2.0f / (1.0f + __expf(-2.0f * cn)) - 1.0f) * s;
                out_h[(size_t)row * DH + col] = hn;
                out_c[(size_t)row * DH + col] = cn;
            }
        }
    }
}

extern "C" void kernel_launch(void* const* d_in, const int* in_sizes, int n_in,
                              void* d_out, int out_size, void* d_ws, size_t ws_size,
                              hipStream_t stream) {
    const float* x  = (const float*)d_in[0];
    const float* h  = (const float*)d_in[1];
    const float* c  = (const float*)d_in[2];
    const float* Wx = (const float*)d_in[3];
    const float* Wh = (const float*)d_in[4];
    const float* b  = (const float*)d_in[5];

    __bf16* A  = (__bf16*)d_ws;                                     // 25,165,824 B
    __bf16* Bt = (__bf16*)((char*)d_ws + (size_t)BROWS * KTOT * 2); // 6,291,456 B

    float* out_h = (float*)d_out;
    float* out_c = out_h + (size_t)BROWS * DH;

    cvtA_kernel<<<(BROWS * (KTOT / 8)) / 256, 256, 0, stream>>>(x, h, A);
    cvtB_kernel<<<dim3(KTOT / 32, 2048 / 32), dim3(32, 8), 0, stream>>>(Wx, Wh, Bt);
    lstm_gemm_kernel<<<256, 512, 0, stream>>>(A, Bt, b, c, out_h, out_c);
}

// Round 16
// 82.512 us; speedup vs baseline: 1.0024x; 1.0024x over previous
//
#include <hip/hip_runtime.h>
#include <hip/hip_bf16.h>
#include <cstdint>

// Problem constants
#define BROWS 8192
#define DIN   512
#define DH    1024
#define KTOT  1536          // DIN + DH
#define NT    (KTOT / 64)   // 24 K-tiles of 64
// Only gate columns [0,2048) are live: g block [0,1024), i block [1024,2048).
// (reference bug: f_out and o_out both use i_in -> f_in/o_in are dead)

typedef __bf16 bf16x8 __attribute__((ext_vector_type(8)));
typedef __bf16 bf16x4 __attribute__((ext_vector_type(4)));
typedef float  f32x16 __attribute__((ext_vector_type(16)));

__device__ __forceinline__ void load16_to_lds(const void* gptr, void* lptr) {
    __builtin_amdgcn_global_load_lds(
        (const __attribute__((address_space(1))) uint32_t*)gptr,
        (__attribute__((address_space(3))) uint32_t*)lptr,
        16, 0, 0);
}

// ---------- Kernel 1: transpose+convert W cols [0,2048) -> bf16 Bt[2048][1536], PRE-SWIZZLED ----------
__global__ __launch_bounds__(256) void cvtB_kernel(
    const float* __restrict__ Wx, const float* __restrict__ Wh,
    __bf16* __restrict__ Bt) {
    __shared__ float tile[32][33];
    int k0 = blockIdx.x * 32;
    int n0 = blockIdx.y * 32;
    int tx = threadIdx.x;   // 0..31
    int ty = threadIdx.y;   // 0..7
#pragma unroll
    for (int i = 0; i < 4; ++i) {
        int k = k0 + ty + 8 * i;
        float v = (k < DIN) ? Wx[(size_t)k * 4096 + n0 + tx]
                            : Wh[(size_t)(k - DIN) * 4096 + n0 + tx];
        tile[ty + 8 * i][tx] = v;
    }
    __syncthreads();
    int n = n0 + tx;
    int kk = ty * 4;
    bf16x4 o = { (__bf16)tile[kk][tx], (__bf16)tile[kk + 1][tx],
                 (__bf16)tile[kk + 2][tx], (__bf16)tile[kk + 3][tx] };
    int swz = ((k0 + kk) * 2) ^ ((n & 7) << 4);
    *(bf16x4*)((char*)Bt + (size_t)n * 3072 + swz) = o;
}

// ---------- Kernel 2: GEMM with FUSED A-conversion + LSTM epilogue ----------
// R15 chassis: tile 256M x 128n' x {g,i}, BK=64, 8 waves (4M x 2N), 32x32x16
// MFMA, 128 KiB LDS dbuf. NEW: A is staged from RAW f32 x|h — per tile each
// thread loads 8x dwordx4 f32, converts, and ds_writes bf16 into the SWIZZLED
// LDS layout (per-lane ds_write: no global_load_lds contiguity law).
// cvtA pass eliminated (-12.5 us serial).
// Per-tile VMEM queue (per thread): [A-f32 x8][B-lds x4], issued at iter start.
//   VMW(12) at iter start  -> B(t) landed (issued one full tile ago)
//   single BARRIER/tile    -> all staging targeted the OTHER buffer
//   VMW(4) after P3        -> A(t+1) f32 regs landed (~3 phases of slack)
//   CVT+DSWRITE -> nb; LGKM0 at iter end (writes drained before next barrier)

#define BARRIER  do { __builtin_amdgcn_sched_barrier(0); __builtin_amdgcn_s_barrier(); __builtin_amdgcn_sched_barrier(0); } while (0)
#define VMW(n)   do { asm volatile("s_waitcnt vmcnt(" #n ")" ::: "memory"); __builtin_amdgcn_sched_barrier(0); } while (0)
#define LGKM0    do { asm volatile("s_waitcnt lgkmcnt(0)" ::: "memory"); __builtin_amdgcn_sched_barrier(0); } while (0)

// A f32 load: rows p*64 + rA, k-cols j8..j8+8 of tile kt. 8 consecutive
// threads cover one row's 256B chunk -> coalesced.
#define ALOAD(kt) do {                                                         \
    const float* base_; size_t str_; int kc_;                                  \
    if ((kt) < 8) { base_ = xp; str_ = 512;  kc_ = (kt) * 64; }                \
    else          { base_ = hp; str_ = 1024; kc_ = ((kt) - 8) * 64; }          \
    _Pragma("unroll")                                                          \
    for (int p_ = 0; p_ < 4; ++p_) {                                           \
        const float* s_ = base_ + (size_t)(brow + p_ * 64 + rA) * str_         \
                          + kc_ + j8;                                          \
        ar[p_][0] = *(const float4*)s_;                                        \
        ar[p_][1] = *(const float4*)(s_ + 4);                                  \
    }                                                                          \
    __builtin_amdgcn_sched_barrier(0);                                         \
} while (0)

// convert + swizzled ds_write into buffer nbuf (slot j, XOR (row&7)<<4):
// per quarter-wave 2 lanes/slot -> conflict-free.
#define CVTWRITE(nbuf) do {                                                    \
    _Pragma("unroll")                                                          \
    for (int p_ = 0; p_ < 4; ++p_) {                                           \
        bf16x8 w_ = { (__bf16)ar[p_][0].x, (__bf16)ar[p_][0].y,                \
                      (__bf16)ar[p_][0].z, (__bf16)ar[p_][0].w,                \
                      (__bf16)ar[p_][1].x, (__bf16)ar[p_][1].y,                \
                      (__bf16)ar[p_][1].z, (__bf16)ar[p_][1].w };              \
        int row_ = p_ * 64 + rA;                                               \
        *(bf16x8*)(sAb + (nbuf) * 32768 + row_ * 128                           \
                   + ((j8 * 2) ^ ((row_ & 7) << 4))) = w_;                     \
    }                                                                          \
    __builtin_amdgcn_sched_barrier(0);                                         \
} while (0)

#define STAGE_B(buf, half, kt) do {                                            \
    const char* g0_ = Bb + (size_t)((half) * 1024 + bnp + r0) * 3072           \
                         + (size_t)(kt) * 128 + cb;                            \
    char* l0_ = sBb + (buf) * 32768 + ((half) * 128 + r0) * 128 + cb;          \
    load16_to_lds(g0_, l0_);                                                   \
    load16_to_lds(g0_ + 64 * 3072, l0_ + 64 * 128);                            \
} while (0)

// 32x32x16 A-frag: lane l -> row l&31, k-half l>>5 (verified R15 layout)
#define READ_A32(dst, c, mh)                                                   \
    _Pragma("unroll")                                                          \
    for (int kf_ = 0; kf_ < 4; ++kf_) {                                        \
        int row_ = wrow + (mh) * 32 + l31;                                     \
        int kb_ = (kf_ * 32 + hi16) ^ ((l31 & 7) << 4);                        \
        dst[kf_] = *(const bf16x8*)(sAb + (c) * 32768 + row_ * 128 + kb_);     \
    }

#define READ_B32(dst, c, half)                                                 \
    _Pragma("unroll")                                                          \
    for (int nq_ = 0; nq_ < 2; ++nq_) {                                        \
        _Pragma("unroll")                                                      \
        for (int kf_ = 0; kf_ < 4; ++kf_) {                                    \
            int row_ = (half) * 128 + wcol + nq_ * 32 + l31;                   \
            int kb_ = (kf_ * 32 + hi16) ^ ((l31 & 7) << 4);                    \
            dst[nq_][kf_] = *(const bf16x8*)(sBb + (c) * 32768 + row_ * 128    \
                                             + kb_);                           \
        }                                                                      \
    }

#define MMA32(ACC, MH, AF, BF) do {                                            \
    __builtin_amdgcn_s_setprio(1);                                             \
    _Pragma("unroll")                                                          \
    for (int kf_ = 0; kf_ < 4; ++kf_) {                                        \
        _Pragma("unroll")                                                      \
        for (int nq_ = 0; nq_ < 2; ++nq_) {                                    \
            ACC[MH][nq_] = __builtin_amdgcn_mfma_f32_32x32x16_bf16(            \
                AF[kf_], BF[nq_][kf_], ACC[MH][nq_], 0, 0, 0);                 \
        }                                                                      \
    }                                                                          \
    __builtin_amdgcn_s_setprio(0);                                             \
    __builtin_amdgcn_sched_barrier(0);                                         \
} while (0)

__global__ __launch_bounds__(512) void lstm_gemm_kernel(
    const float* __restrict__ xp,    // [8192][512]  raw f32
    const float* __restrict__ hp,    // [8192][1024] raw f32
    const __bf16* __restrict__ Bt,   // [2048][1536] pre-swizzled bf16
    const float* __restrict__ bias,  // [4096]
    const float* __restrict__ c_in,  // [8192][1024]
    float* __restrict__ out_h,       // [8192][1024]
    float* __restrict__ out_c) {     // [8192][1024]
    // smem: A dbuf [0, 65536), B dbuf [65536, 131072); row stride 128 B.
    __shared__ char smem[131072];

    const int tid  = threadIdx.x;
    const int lane = tid & 63;
    const int wid  = tid >> 6;
    const int wr   = wid & 3;          // 4 wave-rows
    const int wc   = wid >> 2;         // 2 wave-cols

    // XCD-contiguous band map (R9-proven)
    const int bid   = blockIdx.x;              // 0..255
    const int band  = (bid & 7) * 4 + ((bid >> 3) & 3);  // 0..31
    const int panel = bid >> 5;                          // 0..7
    const int brow  = band * 256;
    const int bnp   = panel * 128;

    const int l31  = lane & 31;
    const int hi   = lane >> 5;        // 0..1
    const int hi16 = hi * 16;
    const int wrow = wr * 64;
    const int wcol = wc * 64;

    // A staging map: rA = tid>>3 (0..63), j8 = (tid&7)*8 elems
    const int rA = tid >> 3;
    const int j8 = (tid & 7) * 8;
    // B staging map (global_load_lds law: chunkBase + lane*16)
    const int r0 = tid >> 3;           // 0..63
    const int cb = (tid & 7) * 16;     // 0..112

    const char* Bb = (const char*)Bt;
    char* sAb = smem;
    char* sBb = smem + 65536;

    f32x16 accg[2][2], acci[2][2];
#pragma unroll
    for (int mh = 0; mh < 2; ++mh)
#pragma unroll
        for (int nq = 0; nq < 2; ++nq)
#pragma unroll
            for (int j = 0; j < 16; ++j) {
                accg[mh][nq][j] = 0.f;
                acci[mh][nq][j] = 0.f;
            }

    float4 ar[4][2];
    bf16x8 aF0[4], aF1[4], bgF[2][4], biF[2][4];

    // Prologue: A(0) via regs -> LDS; B(0) via gload_lds.
    ALOAD(0);
    STAGE_B(0, 0, 0);
    STAGE_B(0, 1, 0);
    VMW(4);                  // A(0) f32 landed (B(0)x4 outstanding)
    CVTWRITE(0);
    LGKM0;

    for (int t = 0; t < NT - 1; ++t) {
        const int c  = t & 1;
        const int nb = c ^ 1;
        ALOAD(t + 1);                    // 8 vmem -> regs
        STAGE_B(nb, 0, t + 1);           // 4 vmem -> other buffer
        STAGE_B(nb, 1, t + 1);
        VMW(12);                         // B(t) landed (issued last iter)
        BARRIER;                         // tile t fully staged, all waves
        // P1
        READ_A32(aF0, c, 0);
        READ_B32(bgF, c, 0);
        LGKM0;
        MMA32(accg, 0, aF0, bgF);
        // P2
        READ_A32(aF1, c, 1);
        LGKM0;
        MMA32(accg, 1, aF1, bgF);
        // P3
        READ_B32(biF, c, 1);
        LGKM0;
        MMA32(acci, 0, aF0, biF);
        // stage A(t+1) into nb while P3's MFMAs run
        VMW(4);                          // A(t+1) f32 landed (B(t+1)x4 left)
        CVTWRITE(nb);
        // P4
        MMA32(acci, 1, aF1, biF);
        LGKM0;                           // ds_writes + reads drained
    }
    {   // last tile: only B(NT-1) outstanding
        const int c = (NT - 1) & 1;
        VMW(0);
        BARRIER;
        READ_A32(aF0, c, 0);
        READ_B32(bgF, c, 0);
        LGKM0;
        MMA32(accg, 0, aF0, bgF);
        READ_A32(aF1, c, 1);
        LGKM0;
        MMA32(accg, 1, aF1, bgF);
        READ_B32(biF, c, 1);
        LGKM0;
        MMA32(acci, 0, aF0, biF);
        MMA32(acci, 1, aF1, biF);
    }

    // Epilogue. 32x32 C/D layout (m74/m101): col = lane&31,
    // row = (r&3) + 8*(r>>2) + 4*(lane>>5), r in [0,16).
    const int R0 = brow + wrow;
    const int C0 = bnp + wcol;
#pragma unroll
    for (int nq = 0; nq < 2; ++nq) {
        const int col = C0 + nq * 32 + l31;
        const float bg = bias[col];
        const float bi = bias[1024 + col];
#pragma unroll
        for (int mh = 0; mh < 2; ++mh) {
#pragma unroll
            for (int r = 0; r < 16; ++r) {
                const int row = R0 + mh * 32 + (r & 3) + 8 * (r >> 2) + 4 * hi;
                const float g_in = accg[mh][nq][r] + bg;
                const float i_in = acci[mh][nq][r] + bi;
                const float s  = 1.0f / (1.0f + __expf(-i_in));
                const float tg = 2.0f / (1.0f + __expf(-2.0f * g_in)) - 1.0f;
                const float cv = c_in[(size_t)row * DH + col];
                const float cn = s * (tg + cv);
                const float hn = (2.0f / (1.0f + __expf(-2.0f * cn)) - 1.0f) * s;
                out_h[(size_t)row * DH + col] = hn;
                out_c[(size_t)row * DH + col] = cn;
            }
        }
    }
}

extern "C" void kernel_launch(void* const* d_in, const int* in_sizes, int n_in,
                              void* d_out, int out_size, void* d_ws, size_t ws_size,
                              hipStream_t stream) {
    const float* x  = (const float*)d_in[0];
    const float* h  = (const float*)d_in[1];
    const float* c  = (const float*)d_in[2];
    const float* Wx = (const float*)d_in[3];
    const float* Wh = (const float*)d_in[4];
    const float* b  = (const float*)d_in[5];

    __bf16* Bt = (__bf16*)d_ws;      // 6,291,456 B

    float* out_h = (float*)d_out;
    float* out_c = out_h + (size_t)BROWS * DH;

    cvtB_kernel<<<dim3(KTOT / 32, 2048 / 32), dim3(32, 8), 0, stream>>>(Wx, Wh, Bt);
    lstm_gemm_kernel<<<256, 512, 0, stream>>>(x, h, Bt, b, c, out_h, out_c);
}